// Round 14
// baseline (489.487 us; speedup 1.0000x reference)
//
#include <hip/hip_runtime.h>
#include <hip/hip_bf16.h>

typedef __attribute__((ext_vector_type(8))) short bf16x8;
typedef __attribute__((ext_vector_type(4))) float f32x4;

constexpr int Bn = 4, Sn = 2048, Dn = 1024, Hn = 16;
constexpr int Mn = Bn * Sn;          // 8192 rows
constexpr float C_SCALE = 0.18033688f;  // (1/8) * log2(e)

static __device__ __forceinline__ unsigned short f2bf(float f) {
  union { float f; unsigned int u; } v; v.f = f;
  unsigned int r = v.u + 0x7fffu + ((v.u >> 16) & 1u);
  return (unsigned short)(r >> 16);
}

static __device__ __forceinline__ unsigned int cvtpk_bf16(float lo, float hi) {
  unsigned int r;
  asm("v_cvt_pk_bf16_f32 %0, %1, %2" : "=v"(r) : "v"(lo), "v"(hi));
  return r;
}

static __device__ __forceinline__ void gload_lds16(const unsigned short* g,
                                                   unsigned short* l) {
  __builtin_amdgcn_global_load_lds(
      (const __attribute__((address_space(1))) unsigned int*)g,
      (__attribute__((address_space(3))) unsigned int*)l,
      16, 0, 0);
}

// ---- fp32 -> bf16 conversion for 3 activations + 4 weights ----
__global__ __launch_bounds__(256)
void cvt7(const float* __restrict__ q, const float* __restrict__ k,
          const float* __restrict__ v, const float* __restrict__ wq,
          const float* __restrict__ wk, const float* __restrict__ wv,
          const float* __restrict__ wo,
          unsigned short* __restrict__ oq, unsigned short* __restrict__ ok,
          unsigned short* __restrict__ ov, unsigned short* __restrict__ owq,
          unsigned short* __restrict__ owk, unsigned short* __restrict__ owv,
          unsigned short* __restrict__ owo)
{
  constexpr size_t NX = (size_t)Mn * Dn;   // 2^23
  constexpr size_t NW = (size_t)Dn * Dn;   // 2^20
  constexpr size_t total = 3 * NX + 4 * NW;
  size_t e = ((size_t)blockIdx.x * blockDim.x + threadIdx.x) * 4;
  const size_t step = (size_t)gridDim.x * blockDim.x * 4;
  for (; e < total; e += step) {
    int seg; size_t off;
    if (e < 3 * NX) { seg = (int)(e >> 23); off = e & (NX - 1); }
    else { const size_t j = e - 3 * NX; seg = 3 + (int)(j >> 20); off = j & (NW - 1); }
    const float* src; unsigned short* dst;
    switch (seg) {
      case 0: src = q;  dst = oq;  break;
      case 1: src = k;  dst = ok;  break;
      case 2: src = v;  dst = ov;  break;
      case 3: src = wq; dst = owq; break;
      case 4: src = wk; dst = owk; break;
      case 5: src = wv; dst = owv; break;
      default: src = wo; dst = owo; break;
    }
    const float4 val = *(const float4*)(src + off);
    ushort4 o;
    o.x = f2bf(val.x); o.y = f2bf(val.y); o.z = f2bf(val.z); o.w = f2bf(val.w);
    *(ushort4*)(dst + off) = o;
  }
}

// ---- GEMM core v2: 128x128 tile, BK=64, swizzled staging ----
static __device__ __forceinline__ void gemm_core(
    const unsigned short* __restrict__ A, const unsigned short* __restrict__ Bw,
    unsigned short* Asl, unsigned short* Bsl,
    int m0, int n0, int wave, int lane, f32x4 (*acc)[4])
{
  const int tid = wave * 64 + lane;
  const int lr = lane & 15, lg = lane >> 4;
  const int wm = wave >> 1, wn = wave & 1;

  for (int k0 = 0; k0 < 1024; k0 += 64) {
    __syncthreads();
    #pragma unroll
    for (int it = 0; it < 4; ++it) {
      const int e = it * 256 + tid;          // 0..1023: row=e>>3, chunk=e&7
      const int row = e >> 3;
      const int col = ((e & 7) ^ (row & 7)) * 8;   // inverse-swizzled source
      gload_lds16(A  + (size_t)(m0 + row) * 1024 + k0 + col,
                  &Asl[(it * 256 + wave * 64) * 8]);
      gload_lds16(Bw + (size_t)(n0 + row) * 1024 + k0 + col,
                  &Bsl[(it * 256 + wave * 64) * 8]);
    }
    __syncthreads();

    #pragma unroll
    for (int kk = 0; kk < 2; ++kk) {
      const int ch = ((kk * 4 + lg) ^ (lr & 7)) * 8;  // swizzled read chunk
      bf16x8 af[4], bfr[4];
      #pragma unroll
      for (int mf = 0; mf < 4; ++mf)
        af[mf] = *(const bf16x8*)&Asl[(wm * 64 + mf * 16 + lr) * 64 + ch];
      #pragma unroll
      for (int nf = 0; nf < 4; ++nf)
        bfr[nf] = *(const bf16x8*)&Bsl[(wn * 64 + nf * 16 + lr) * 64 + ch];
      #pragma unroll
      for (int mf = 0; mf < 4; ++mf)
        #pragma unroll
        for (int nf = 0; nf < 4; ++nf)
          acc[mf][nf] = __builtin_amdgcn_mfma_f32_16x16x32_bf16(
              af[mf], bfr[nf], acc[mf][nf], 0, 0, 0);
    }
  }
}

// ---- fused Q/K/V projection: z=0 Q (pre-scaled by C_SCALE), z=1 K, z=2 V->Vt
__global__ __launch_bounds__(256)
void gemm_qkv(const unsigned short* __restrict__ Xq,
              const unsigned short* __restrict__ Xk,
              const unsigned short* __restrict__ Xv,
              const unsigned short* __restrict__ Wq,
              const unsigned short* __restrict__ Wk,
              const unsigned short* __restrict__ Wv,
              unsigned short* __restrict__ Qbf,
              unsigned short* __restrict__ Kbf,
              unsigned short* __restrict__ Vtb)
{
  __shared__ unsigned short ShBuf[128 * 136];
  unsigned short* Asl = ShBuf;
  unsigned short* Bsl = ShBuf + 128 * 64;

  const int tid  = threadIdx.x;
  const int wave = tid >> 6, lane = tid & 63;
  const int lr = lane & 15, lg = lane >> 4;
  const int wm = wave >> 1, wn = wave & 1;
  const int m0 = blockIdx.x * 128;
  const int n0 = blockIdx.y * 128;
  const int z  = blockIdx.z;

  const unsigned short* A  = (z == 0) ? Xq : (z == 1) ? Xk : Xv;
  const unsigned short* Bw = (z == 0) ? Wq : (z == 1) ? Wk : Wv;

  f32x4 acc[4][4] = {};
  gemm_core(A, Bw, Asl, Bsl, m0, n0, wave, lane, acc);

  if (z < 2) {
    unsigned short* C = (z == 0) ? Qbf : Kbf;
    const float cs = (z == 0) ? C_SCALE : 1.0f;   // fold softmax scale into Q
    #pragma unroll
    for (int mf = 0; mf < 4; ++mf)
      #pragma unroll
      for (int nf = 0; nf < 4; ++nf)
        #pragma unroll
        for (int i = 0; i < 4; ++i) {
          const int row = m0 + wm * 64 + mf * 16 + lg * 4 + i;
          const int col = n0 + wn * 64 + nf * 16 + lr;
          C[(size_t)row * 1024 + col] = f2bf(acc[mf][nf][i] * cs);
        }
  } else {
    unsigned short (*Ts)[136] = (unsigned short (*)[136])ShBuf;
    __syncthreads();   // all waves done reading Asl/Bsl before overwrite
    #pragma unroll
    for (int mf = 0; mf < 4; ++mf)
      #pragma unroll
      for (int nf = 0; nf < 4; ++nf)
        #pragma unroll
        for (int i = 0; i < 4; ++i)
          Ts[wn * 64 + nf * 16 + lr][wm * 64 + mf * 16 + lg * 4 + i] =
              f2bf(acc[mf][nf][i]);
    __syncthreads();
    const int dkl = tid >> 1;                 // 0..127 local d index
    const int sh  = (tid & 1) * 64;           // s half
    const int b = m0 >> 11, s0 = m0 & 2047;
    const int gcol = n0 + dkl;
    const int h = gcol >> 6, dk = gcol & 63;
    unsigned short* dst =
        Vtb + ((size_t)((b * 16 + h) * 64 + dk)) * Sn + s0 + sh;
    #pragma unroll
    for (int jj = 0; jj < 8; ++jj)
      *(bf16x8*)(dst + jj * 8) = *(const bf16x8*)&Ts[dkl][sh + jj * 8];
  }
}

// ---- output projection: f32 + bias ----
__global__ __launch_bounds__(256)
void gemm_o(const unsigned short* __restrict__ A,
            const unsigned short* __restrict__ Bw,
            float* __restrict__ C, const float* __restrict__ bias)
{
  __shared__ unsigned short Asl[128 * 64];
  __shared__ unsigned short Bsl[128 * 64];
  const int tid  = threadIdx.x;
  const int wave = tid >> 6, lane = tid & 63;
  const int lr = lane & 15, lg = lane >> 4;
  const int wm = wave >> 1, wn = wave & 1;
  const int m0 = blockIdx.x * 128;
  const int n0 = blockIdx.y * 128;

  f32x4 acc[4][4] = {};
  gemm_core(A, Bw, Asl, Bsl, m0, n0, wave, lane, acc);

  float bv[4];
  #pragma unroll
  for (int nf = 0; nf < 4; ++nf) bv[nf] = bias[n0 + wn * 64 + nf * 16 + lr];
  #pragma unroll
  for (int mf = 0; mf < 4; ++mf)
    #pragma unroll
    for (int nf = 0; nf < 4; ++nf)
      #pragma unroll
      for (int i = 0; i < 4; ++i) {
        const int row = m0 + wm * 64 + mf * 16 + lg * 4 + i;
        const int col = n0 + wn * 64 + nf * 16 + lr;
        C[(size_t)row * 1024 + col] = acc[mf][nf][i] + bv[nf];
      }
}

// ---- fused causal attention, SWAPPED QK^T, 64-row strips (4x K/V reuse) ----
// Each wave owns a 64-row q-strip as four 16-row halves sharing the K/V
// fragment loads. Strips paired {j, 31-j}: nkt(j)+nkt(31-j) == 33 exactly.
__global__ __launch_bounds__(128)
void attn_fused(const unsigned short* __restrict__ Qb,
                const unsigned short* __restrict__ Kb,
                const unsigned short* __restrict__ Vt,
                float* __restrict__ attn_out,
                unsigned short* __restrict__ Ob)
{
  __shared__ unsigned short Ps[2][64][88];   // [wave][64 q-rows][64 keys+pad]

  const int tid = threadIdx.x;
  const int w = tid >> 6, lane = tid & 63;
  const int lr = lane & 15, lg = lane >> 4;
  const int bh = blockIdx.x >> 4;
  const int j  = blockIdx.x & 15;
  const int qs = w ? (31 - j) : j;       // paired q-strips: equal block work
  const int b = bh >> 4, h = bh & 15;
  const int q0 = qs * 64;
  const int nkt = qs + 1;                // K-tiles with any unmasked key
  const int kl  = nkt - 1;               // the only partially-masked tile

  const unsigned short* Kbh = Kb + (size_t)(b * Sn) * Dn + h * 64;
  const unsigned short* Vbh = Vt + (size_t)(bh * 64) * Sn;
  float* aout = attn_out + (size_t)bh * Sn * (size_t)Sn;

  bf16x8 qf[4][2];
  #pragma unroll
  for (int hf = 0; hf < 4; ++hf) {
    const int qoff = (b * Sn + q0 + hf * 16 + lr) * Dn + h * 64 + lg * 8;
    qf[hf][0] = *(const bf16x8*)(Qb + qoff);
    qf[hf][1] = *(const bf16x8*)(Qb + qoff + 32);
  }

  float l[4] = {0.f, 0.f, 0.f, 0.f};

  // ---- pass 1: denominators (K loads shared by all four 16-row halves) ----
  for (int kt = 0; kt < kl; ++kt) {
    bf16x8 kf[4][2];
    #pragma unroll
    for (int nf = 0; nf < 4; ++nf)
      #pragma unroll
      for (int kk = 0; kk < 2; ++kk)
        kf[nf][kk] = *(const bf16x8*)(
            Kbh + (kt * 64 + nf * 16 + lr) * Dn + kk * 32 + lg * 8);
    #pragma unroll
    for (int hf = 0; hf < 4; ++hf)
      #pragma unroll
      for (int nf = 0; nf < 4; ++nf) {
        f32x4 a = {0.f, 0.f, 0.f, 0.f};
        a = __builtin_amdgcn_mfma_f32_16x16x32_bf16(kf[nf][0], qf[hf][0], a, 0, 0, 0);
        a = __builtin_amdgcn_mfma_f32_16x16x32_bf16(kf[nf][1], qf[hf][1], a, 0, 0, 0);
        l[hf] += (exp2f(a[0]) + exp2f(a[1])) + (exp2f(a[2]) + exp2f(a[3]));
      }
  }
  { // last tile: masked
    bf16x8 kf[4][2];
    #pragma unroll
    for (int nf = 0; nf < 4; ++nf)
      #pragma unroll
      for (int kk = 0; kk < 2; ++kk)
        kf[nf][kk] = *(const bf16x8*)(
            Kbh + (kl * 64 + nf * 16 + lr) * Dn + kk * 32 + lg * 8);
    #pragma unroll
    for (int hf = 0; hf < 4; ++hf) {
      const int q = q0 + hf * 16 + lr;
      #pragma unroll
      for (int nf = 0; nf < 4; ++nf) {
        f32x4 a = {0.f, 0.f, 0.f, 0.f};
        a = __builtin_amdgcn_mfma_f32_16x16x32_bf16(kf[nf][0], qf[hf][0], a, 0, 0, 0);
        a = __builtin_amdgcn_mfma_f32_16x16x32_bf16(kf[nf][1], qf[hf][1], a, 0, 0, 0);
        #pragma unroll
        for (int i = 0; i < 4; ++i) {
          const int key = kl * 64 + nf * 16 + lg * 4 + i;
          l[hf] += (key <= q) ? exp2f(a[i]) : 0.f;
        }
      }
    }
  }
  // reduce over the 4 lanes (lg) sharing each q-row
  float nlg[4];
  #pragma unroll
  for (int hf = 0; hf < 4; ++hf) {
    l[hf] += __shfl_xor(l[hf], 16, 64);
    l[hf] += __shfl_xor(l[hf], 32, 64);
    nlg[hf] = -log2f(l[hf]);
  }

  // ---- pass 2: NT attn store + PV (K/V loads shared by all halves) ----
  f32x4 oacc[4][4] = {};
  for (int kt = 0; kt < nkt; ++kt) {
    const bool last = (kt == kl);
    bf16x8 kf[4][2], vt[4][2];
    #pragma unroll
    for (int nf = 0; nf < 4; ++nf)
      #pragma unroll
      for (int kk = 0; kk < 2; ++kk) {
        kf[nf][kk] = *(const bf16x8*)(
            Kbh + (kt * 64 + nf * 16 + lr) * Dn + kk * 32 + lg * 8);
        vt[nf][kk] = *(const bf16x8*)(
            Vbh + (nf * 16 + lr) * Sn + kt * 64 + kk * 32 + lg * 8);
      }
    #pragma unroll
    for (int hf = 0; hf < 4; ++hf) {
      const int q = q0 + hf * 16 + lr;
      #pragma unroll
      for (int nf = 0; nf < 4; ++nf) {
        f32x4 a = {0.f, 0.f, 0.f, 0.f};
        a = __builtin_amdgcn_mfma_f32_16x16x32_bf16(kf[nf][0], qf[hf][0], a, 0, 0, 0);
        a = __builtin_amdgcn_mfma_f32_16x16x32_bf16(kf[nf][1], qf[hf][1], a, 0, 0, 0);
        f32x4 p4;
        if (!last) {
          #pragma unroll
          for (int i = 0; i < 4; ++i) p4[i] = exp2f(a[i] + nlg[hf]);
        } else {
          #pragma unroll
          for (int i = 0; i < 4; ++i) {
            const int key = kl * 64 + nf * 16 + lg * 4 + i;
            const float v = exp2f(a[i] + nlg[hf]);
            p4[i] = (key <= q) ? v : 0.f;
          }
        }
        __builtin_nontemporal_store(
            p4, (f32x4*)&aout[q * Sn + kt * 64 + nf * 16 + lg * 4]);
        uint2 pk;
        pk.x = cvtpk_bf16(p4[0], p4[1]);
        pk.y = cvtpk_bf16(p4[2], p4[3]);
        *(uint2*)&Ps[w][hf * 16 + lr][nf * 16 + lg * 4] = pk;
      }
    }
    // PV for all halves (same-wave LDS write->read, in-order)
    #pragma unroll
    for (int hf = 0; hf < 4; ++hf) {
      bf16x8 pa[2];
      pa[0] = *(const bf16x8*)&Ps[w][hf * 16 + lr][lg * 8];
      pa[1] = *(const bf16x8*)&Ps[w][hf * 16 + lr][32 + lg * 8];
      #pragma unroll
      for (int kk = 0; kk < 2; ++kk)
        #pragma unroll
        for (int nf = 0; nf < 4; ++nf)
          oacc[hf][nf] = __builtin_amdgcn_mfma_f32_16x16x32_bf16(
              pa[kk], vt[nf][kk], oacc[hf][nf], 0, 0, 0);
    }
  }
  // fully-masked tiles: contiguous NT zero stores (64 rows/tile)
  for (int kt = nkt; kt < Sn / 64; ++kt) {
    const f32x4 z = {0.f, 0.f, 0.f, 0.f};
    #pragma unroll
    for (int jj = 0; jj < 16; ++jj) {
      const int r = q0 + lg + 4 * jj;
      __builtin_nontemporal_store(
          z, (f32x4*)&aout[r * Sn + kt * 64 + lr * 4]);
    }
  }
  #pragma unroll
  for (int hf = 0; hf < 4; ++hf)
    #pragma unroll
    for (int nf = 0; nf < 4; ++nf)
      #pragma unroll
      for (int i = 0; i < 4; ++i) {
        const int qq = q0 + hf * 16 + lg * 4 + i;
        const int dk = nf * 16 + lr;
        Ob[(b * Sn + qq) * Dn + h * 64 + dk] = f2bf(oacc[hf][nf][i]);
      }
}

extern "C" void kernel_launch(void* const* d_in, const int* in_sizes, int n_in,
                              void* d_out, int out_size, void* d_ws, size_t ws_size,
                              hipStream_t stream)
{
  const float* query = (const float*)d_in[0];
  const float* key   = (const float*)d_in[1];
  const float* value = (const float*)d_in[2];
  // d_in[3] = mask: causal tril, handled analytically
  const float* w_q = (const float*)d_in[4];
  const float* w_k = (const float*)d_in[5];
  const float* w_v = (const float*)d_in[6];
  const float* w_o = (const float*)d_in[7];
  const float* b_o = (const float*)d_in[8];

  constexpr size_t NX = (size_t)Mn * Dn;
  constexpr size_t NW = (size_t)Dn * Dn;
  unsigned short* Xq  = (unsigned short*)d_ws;
  unsigned short* Xk  = Xq  + NX;
  unsigned short* Xv  = Xk  + NX;
  unsigned short* Wq  = Xv  + NX;
  unsigned short* Wk  = Wq  + NW;
  unsigned short* Wv  = Wk  + NW;
  unsigned short* Wo  = Wv  + NW;
  unsigned short* Qbf = Wo  + NW;
  unsigned short* Kbf = Qbf + NX;
  unsigned short* Vtb = Kbf + NX;
  unsigned short* Obf = Vtb + NX;

  float* out  = (float*)d_out;
  float* attn = out + NX;

  cvt7<<<dim3(2048), dim3(256), 0, stream>>>(query, key, value, w_q, w_k, w_v, w_o,
                                             Xq, Xk, Xv, Wq, Wk, Wv, Wo);
  gemm_qkv<<<dim3(Mn / 128, Dn / 128, 3), dim3(256), 0, stream>>>(
      Xq, Xk, Xv, Wq, Wk, Wv, Qbf, Kbf, Vtb);
  attn_fused<<<dim3(64 * 16), dim3(128), 0, stream>>>(Qbf, Kbf, Vtb, attn, Obf);
  gemm_o<<<dim3(Mn / 128, Dn / 128), dim3(256), 0, stream>>>(Obf, Wo, out, b_o);
}

// Round 15
// 451.618 us; speedup vs baseline: 1.0839x; 1.0839x over previous
//
#include <hip/hip_runtime.h>
#include <hip/hip_bf16.h>

typedef __attribute__((ext_vector_type(8))) short bf16x8;
typedef __attribute__((ext_vector_type(4))) float f32x4;

constexpr int Bn = 4, Sn = 2048, Dn = 1024, Hn = 16;
constexpr int Mn = Bn * Sn;          // 8192 rows
constexpr float C_SCALE = 0.18033688f;  // (1/8) * log2(e)

static __device__ __forceinline__ unsigned short f2bf(float f) {
  union { float f; unsigned int u; } v; v.f = f;
  unsigned int r = v.u + 0x7fffu + ((v.u >> 16) & 1u);
  return (unsigned short)(r >> 16);
}

static __device__ __forceinline__ unsigned int cvtpk_bf16(float lo, float hi) {
  unsigned int r;
  asm("v_cvt_pk_bf16_f32 %0, %1, %2" : "=v"(r) : "v"(lo), "v"(hi));
  return r;
}

static __device__ __forceinline__ void gload_lds16(const unsigned short* g,
                                                   unsigned short* l) {
  __builtin_amdgcn_global_load_lds(
      (const __attribute__((address_space(1))) unsigned int*)g,
      (__attribute__((address_space(3))) unsigned int*)l,
      16, 0, 0);
}

// ---- fp32 -> bf16 conversion for 3 activations + 4 weights ----
__global__ __launch_bounds__(256)
void cvt7(const float* __restrict__ q, const float* __restrict__ k,
          const float* __restrict__ v, const float* __restrict__ wq,
          const float* __restrict__ wk, const float* __restrict__ wv,
          const float* __restrict__ wo,
          unsigned short* __restrict__ oq, unsigned short* __restrict__ ok,
          unsigned short* __restrict__ ov, unsigned short* __restrict__ owq,
          unsigned short* __restrict__ owk, unsigned short* __restrict__ owv,
          unsigned short* __restrict__ owo)
{
  constexpr size_t NX = (size_t)Mn * Dn;   // 2^23
  constexpr size_t NW = (size_t)Dn * Dn;   // 2^20
  constexpr size_t total = 3 * NX + 4 * NW;
  size_t e = ((size_t)blockIdx.x * blockDim.x + threadIdx.x) * 4;
  const size_t step = (size_t)gridDim.x * blockDim.x * 4;
  for (; e < total; e += step) {
    int seg; size_t off;
    if (e < 3 * NX) { seg = (int)(e >> 23); off = e & (NX - 1); }
    else { const size_t j = e - 3 * NX; seg = 3 + (int)(j >> 20); off = j & (NW - 1); }
    const float* src; unsigned short* dst;
    switch (seg) {
      case 0: src = q;  dst = oq;  break;
      case 1: src = k;  dst = ok;  break;
      case 2: src = v;  dst = ov;  break;
      case 3: src = wq; dst = owq; break;
      case 4: src = wk; dst = owk; break;
      case 5: src = wv; dst = owv; break;
      default: src = wo; dst = owo; break;
    }
    const float4 val = *(const float4*)(src + off);
    ushort4 o;
    o.x = f2bf(val.x); o.y = f2bf(val.y); o.z = f2bf(val.z); o.w = f2bf(val.w);
    *(ushort4*)(dst + off) = o;
  }
}

// ---- GEMM core v2: 128x128 tile, BK=64, swizzled staging ----
static __device__ __forceinline__ void gemm_core(
    const unsigned short* __restrict__ A, const unsigned short* __restrict__ Bw,
    unsigned short* Asl, unsigned short* Bsl,
    int m0, int n0, int wave, int lane, f32x4 (*acc)[4])
{
  const int tid = wave * 64 + lane;
  const int lr = lane & 15, lg = lane >> 4;
  const int wm = wave >> 1, wn = wave & 1;

  for (int k0 = 0; k0 < 1024; k0 += 64) {
    __syncthreads();
    #pragma unroll
    for (int it = 0; it < 4; ++it) {
      const int e = it * 256 + tid;          // 0..1023: row=e>>3, chunk=e&7
      const int row = e >> 3;
      const int col = ((e & 7) ^ (row & 7)) * 8;   // inverse-swizzled source
      gload_lds16(A  + (size_t)(m0 + row) * 1024 + k0 + col,
                  &Asl[(it * 256 + wave * 64) * 8]);
      gload_lds16(Bw + (size_t)(n0 + row) * 1024 + k0 + col,
                  &Bsl[(it * 256 + wave * 64) * 8]);
    }
    __syncthreads();

    #pragma unroll
    for (int kk = 0; kk < 2; ++kk) {
      const int ch = ((kk * 4 + lg) ^ (lr & 7)) * 8;  // swizzled read chunk
      bf16x8 af[4], bfr[4];
      #pragma unroll
      for (int mf = 0; mf < 4; ++mf)
        af[mf] = *(const bf16x8*)&Asl[(wm * 64 + mf * 16 + lr) * 64 + ch];
      #pragma unroll
      for (int nf = 0; nf < 4; ++nf)
        bfr[nf] = *(const bf16x8*)&Bsl[(wn * 64 + nf * 16 + lr) * 64 + ch];
      #pragma unroll
      for (int mf = 0; mf < 4; ++mf)
        #pragma unroll
        for (int nf = 0; nf < 4; ++nf)
          acc[mf][nf] = __builtin_amdgcn_mfma_f32_16x16x32_bf16(
              af[mf], bfr[nf], acc[mf][nf], 0, 0, 0);
    }
  }
}

// ---- fused Q/K/V projection: z=0 Q (pre-scaled by C_SCALE), z=1 K, z=2 V->Vt
__global__ __launch_bounds__(256)
void gemm_qkv(const unsigned short* __restrict__ Xq,
              const unsigned short* __restrict__ Xk,
              const unsigned short* __restrict__ Xv,
              const unsigned short* __restrict__ Wq,
              const unsigned short* __restrict__ Wk,
              const unsigned short* __restrict__ Wv,
              unsigned short* __restrict__ Qbf,
              unsigned short* __restrict__ Kbf,
              unsigned short* __restrict__ Vtb)
{
  __shared__ unsigned short ShBuf[128 * 136];
  unsigned short* Asl = ShBuf;
  unsigned short* Bsl = ShBuf + 128 * 64;

  const int tid  = threadIdx.x;
  const int wave = tid >> 6, lane = tid & 63;
  const int lr = lane & 15, lg = lane >> 4;
  const int wm = wave >> 1, wn = wave & 1;
  const int m0 = blockIdx.x * 128;
  const int n0 = blockIdx.y * 128;
  const int z  = blockIdx.z;

  const unsigned short* A  = (z == 0) ? Xq : (z == 1) ? Xk : Xv;
  const unsigned short* Bw = (z == 0) ? Wq : (z == 1) ? Wk : Wv;

  f32x4 acc[4][4] = {};
  gemm_core(A, Bw, Asl, Bsl, m0, n0, wave, lane, acc);

  if (z < 2) {
    unsigned short* C = (z == 0) ? Qbf : Kbf;
    const float cs = (z == 0) ? C_SCALE : 1.0f;   // fold softmax scale into Q
    #pragma unroll
    for (int mf = 0; mf < 4; ++mf)
      #pragma unroll
      for (int nf = 0; nf < 4; ++nf)
        #pragma unroll
        for (int i = 0; i < 4; ++i) {
          const int row = m0 + wm * 64 + mf * 16 + lg * 4 + i;
          const int col = n0 + wn * 64 + nf * 16 + lr;
          C[(size_t)row * 1024 + col] = f2bf(acc[mf][nf][i] * cs);
        }
  } else {
    unsigned short (*Ts)[136] = (unsigned short (*)[136])ShBuf;
    __syncthreads();   // all waves done reading Asl/Bsl before overwrite
    #pragma unroll
    for (int mf = 0; mf < 4; ++mf)
      #pragma unroll
      for (int nf = 0; nf < 4; ++nf)
        #pragma unroll
        for (int i = 0; i < 4; ++i)
          Ts[wn * 64 + nf * 16 + lr][wm * 64 + mf * 16 + lg * 4 + i] =
              f2bf(acc[mf][nf][i]);
    __syncthreads();
    const int dkl = tid >> 1;                 // 0..127 local d index
    const int sh  = (tid & 1) * 64;           // s half
    const int b = m0 >> 11, s0 = m0 & 2047;
    const int gcol = n0 + dkl;
    const int h = gcol >> 6, dk = gcol & 63;
    unsigned short* dst =
        Vtb + ((size_t)((b * 16 + h) * 64 + dk)) * Sn + s0 + sh;
    #pragma unroll
    for (int jj = 0; jj < 8; ++jj)
      *(bf16x8*)(dst + jj * 8) = *(const bf16x8*)&Ts[dkl][sh + jj * 8];
  }
}

// ---- output projection: f32 + bias ----
__global__ __launch_bounds__(256)
void gemm_o(const unsigned short* __restrict__ A,
            const unsigned short* __restrict__ Bw,
            float* __restrict__ C, const float* __restrict__ bias)
{
  __shared__ unsigned short Asl[128 * 64];
  __shared__ unsigned short Bsl[128 * 64];
  const int tid  = threadIdx.x;
  const int wave = tid >> 6, lane = tid & 63;
  const int lr = lane & 15, lg = lane >> 4;
  const int wm = wave >> 1, wn = wave & 1;
  const int m0 = blockIdx.x * 128;
  const int n0 = blockIdx.y * 128;

  f32x4 acc[4][4] = {};
  gemm_core(A, Bw, Asl, Bsl, m0, n0, wave, lane, acc);

  float bv[4];
  #pragma unroll
  for (int nf = 0; nf < 4; ++nf) bv[nf] = bias[n0 + wn * 64 + nf * 16 + lr];
  #pragma unroll
  for (int mf = 0; mf < 4; ++mf)
    #pragma unroll
    for (int nf = 0; nf < 4; ++nf)
      #pragma unroll
      for (int i = 0; i < 4; ++i) {
        const int row = m0 + wm * 64 + mf * 16 + lg * 4 + i;
        const int col = n0 + wn * 64 + nf * 16 + lr;
        C[(size_t)row * 1024 + col] = acc[mf][nf][i] + bv[nf];
      }
}

// ---- fused causal attention, SWAPPED QK^T, 32-row strips (R13) ----
// + XCD-aware block swizzle (bh's 32 blocks co-located per XCD -> K/V L2-hot)
// + setprio(1) around MFMA clusters (independent-wave regime, m191)
__global__ __launch_bounds__(128)
void attn_fused(const unsigned short* __restrict__ Qb,
                const unsigned short* __restrict__ Kb,
                const unsigned short* __restrict__ Vt,
                float* __restrict__ attn_out,
                unsigned short* __restrict__ Ob)
{
  __shared__ unsigned short Ps[2][32][88];   // [wave][32 q-rows][64 keys+pad]

  const int tid = threadIdx.x;
  const int w = tid >> 6, lane = tid & 63;
  const int lr = lane & 15, lg = lane >> 4;
  // XCD swizzle: nwg=2048 divisible by 8 -> bijective remap.
  // wg = xcd*256 + orig/8 groups each bh's 32 blocks onto one XCD.
  const int wg = (blockIdx.x & 7) * 256 + (blockIdx.x >> 3);
  const int bh = wg >> 5;
  const int j  = wg & 31;
  const int qs = w ? (63 - j) : j;       // paired q-strips: equal block work
  const int b = bh >> 4, h = bh & 15;
  const int q0 = qs * 32;
  const int nkt = (q0 + 31) / 64 + 1;
  const int kl  = nkt - 1;               // the only partially-masked tile

  const unsigned short* Kbh = Kb + (size_t)(b * Sn) * Dn + h * 64;
  const unsigned short* Vbh = Vt + (size_t)(bh * 64) * Sn;
  float* aout = attn_out + (size_t)bh * Sn * (size_t)Sn;

  bf16x8 qf[2][2];
  #pragma unroll
  for (int hf = 0; hf < 2; ++hf) {
    const int qoff = (b * Sn + q0 + hf * 16 + lr) * Dn + h * 64 + lg * 8;
    qf[hf][0] = *(const bf16x8*)(Qb + qoff);
    qf[hf][1] = *(const bf16x8*)(Qb + qoff + 32);
  }

  float l[2] = {0.f, 0.f};

  // ---- pass 1: denominators (K loads shared by both 16-row halves) ----
  for (int kt = 0; kt < kl; ++kt) {
    bf16x8 kf[4][2];
    #pragma unroll
    for (int nf = 0; nf < 4; ++nf)
      #pragma unroll
      for (int kk = 0; kk < 2; ++kk)
        kf[nf][kk] = *(const bf16x8*)(
            Kbh + (kt * 64 + nf * 16 + lr) * Dn + kk * 32 + lg * 8);
    __builtin_amdgcn_s_setprio(1);
    #pragma unroll
    for (int hf = 0; hf < 2; ++hf)
      #pragma unroll
      for (int nf = 0; nf < 4; ++nf) {
        f32x4 a = {0.f, 0.f, 0.f, 0.f};
        a = __builtin_amdgcn_mfma_f32_16x16x32_bf16(kf[nf][0], qf[hf][0], a, 0, 0, 0);
        a = __builtin_amdgcn_mfma_f32_16x16x32_bf16(kf[nf][1], qf[hf][1], a, 0, 0, 0);
        l[hf] += (exp2f(a[0]) + exp2f(a[1])) + (exp2f(a[2]) + exp2f(a[3]));
      }
    __builtin_amdgcn_s_setprio(0);
  }
  { // last tile: masked
    bf16x8 kf[4][2];
    #pragma unroll
    for (int nf = 0; nf < 4; ++nf)
      #pragma unroll
      for (int kk = 0; kk < 2; ++kk)
        kf[nf][kk] = *(const bf16x8*)(
            Kbh + (kl * 64 + nf * 16 + lr) * Dn + kk * 32 + lg * 8);
    #pragma unroll
    for (int hf = 0; hf < 2; ++hf) {
      const int q = q0 + hf * 16 + lr;
      #pragma unroll
      for (int nf = 0; nf < 4; ++nf) {
        f32x4 a = {0.f, 0.f, 0.f, 0.f};
        a = __builtin_amdgcn_mfma_f32_16x16x32_bf16(kf[nf][0], qf[hf][0], a, 0, 0, 0);
        a = __builtin_amdgcn_mfma_f32_16x16x32_bf16(kf[nf][1], qf[hf][1], a, 0, 0, 0);
        #pragma unroll
        for (int i = 0; i < 4; ++i) {
          const int key = kl * 64 + nf * 16 + lg * 4 + i;
          l[hf] += (key <= q) ? exp2f(a[i]) : 0.f;
        }
      }
    }
  }
  // reduce over the 4 lanes (lg) sharing each q-row
  float nlg[2];
  #pragma unroll
  for (int hf = 0; hf < 2; ++hf) {
    l[hf] += __shfl_xor(l[hf], 16, 64);
    l[hf] += __shfl_xor(l[hf], 32, 64);
    nlg[hf] = -log2f(l[hf]);
  }

  // ---- pass 2: NT attn store + PV (K/V loads shared by both halves) ----
  f32x4 oacc[2][4] = {};
  for (int kt = 0; kt < nkt; ++kt) {
    const bool last = (kt == kl);
    bf16x8 kf[4][2], vt[4][2];
    #pragma unroll
    for (int nf = 0; nf < 4; ++nf)
      #pragma unroll
      for (int kk = 0; kk < 2; ++kk) {
        kf[nf][kk] = *(const bf16x8*)(
            Kbh + (kt * 64 + nf * 16 + lr) * Dn + kk * 32 + lg * 8);
        vt[nf][kk] = *(const bf16x8*)(
            Vbh + (nf * 16 + lr) * Sn + kt * 64 + kk * 32 + lg * 8);
      }
    #pragma unroll
    for (int hf = 0; hf < 2; ++hf) {
      const int q = q0 + hf * 16 + lr;
      __builtin_amdgcn_s_setprio(1);
      #pragma unroll
      for (int nf = 0; nf < 4; ++nf) {
        f32x4 a = {0.f, 0.f, 0.f, 0.f};
        a = __builtin_amdgcn_mfma_f32_16x16x32_bf16(kf[nf][0], qf[hf][0], a, 0, 0, 0);
        a = __builtin_amdgcn_mfma_f32_16x16x32_bf16(kf[nf][1], qf[hf][1], a, 0, 0, 0);
        f32x4 p4;
        if (!last) {
          #pragma unroll
          for (int i = 0; i < 4; ++i) p4[i] = exp2f(a[i] + nlg[hf]);
        } else {
          #pragma unroll
          for (int i = 0; i < 4; ++i) {
            const int key = kl * 64 + nf * 16 + lg * 4 + i;
            const float v = exp2f(a[i] + nlg[hf]);
            p4[i] = (key <= q) ? v : 0.f;
          }
        }
        __builtin_nontemporal_store(
            p4, (f32x4*)&aout[q * Sn + kt * 64 + nf * 16 + lg * 4]);
        uint2 pk;
        pk.x = cvtpk_bf16(p4[0], p4[1]);
        pk.y = cvtpk_bf16(p4[2], p4[3]);
        *(uint2*)&Ps[w][hf * 16 + lr][nf * 16 + lg * 4] = pk;
      }
      __builtin_amdgcn_s_setprio(0);
    }
    // PV for both halves (same-wave LDS write->read, in-order)
    __builtin_amdgcn_s_setprio(1);
    #pragma unroll
    for (int hf = 0; hf < 2; ++hf) {
      bf16x8 pa[2];
      pa[0] = *(const bf16x8*)&Ps[w][hf * 16 + lr][lg * 8];
      pa[1] = *(const bf16x8*)&Ps[w][hf * 16 + lr][32 + lg * 8];
      #pragma unroll
      for (int kk = 0; kk < 2; ++kk)
        #pragma unroll
        for (int nf = 0; nf < 4; ++nf)
          oacc[hf][nf] = __builtin_amdgcn_mfma_f32_16x16x32_bf16(
              pa[kk], vt[nf][kk], oacc[hf][nf], 0, 0, 0);
    }
    __builtin_amdgcn_s_setprio(0);
  }
  // fully-masked tiles: contiguous NT zero stores (32 rows/tile)
  for (int kt = nkt; kt < Sn / 64; ++kt) {
    const f32x4 z = {0.f, 0.f, 0.f, 0.f};
    #pragma unroll
    for (int jj = 0; jj < 8; ++jj) {
      const int r = q0 + lg + 4 * jj;
      __builtin_nontemporal_store(
          z, (f32x4*)&aout[r * Sn + kt * 64 + lr * 4]);
    }
  }
  #pragma unroll
  for (int hf = 0; hf < 2; ++hf)
    #pragma unroll
    for (int nf = 0; nf < 4; ++nf)
      #pragma unroll
      for (int i = 0; i < 4; ++i) {
        const int qq = q0 + hf * 16 + lg * 4 + i;
        const int dk = nf * 16 + lr;
        Ob[(b * Sn + qq) * Dn + h * 64 + dk] = f2bf(oacc[hf][nf][i]);
      }
}

extern "C" void kernel_launch(void* const* d_in, const int* in_sizes, int n_in,
                              void* d_out, int out_size, void* d_ws, size_t ws_size,
                              hipStream_t stream)
{
  const float* query = (const float*)d_in[0];
  const float* key   = (const float*)d_in[1];
  const float* value = (const float*)d_in[2];
  // d_in[3] = mask: causal tril, handled analytically
  const float* w_q = (const float*)d_in[4];
  const float* w_k = (const float*)d_in[5];
  const float* w_v = (const float*)d_in[6];
  const float* w_o = (const float*)d_in[7];
  const float* b_o = (const float*)d_in[8];

  constexpr size_t NX = (size_t)Mn * Dn;
  constexpr size_t NW = (size_t)Dn * Dn;
  unsigned short* Xq  = (unsigned short*)d_ws;
  unsigned short* Xk  = Xq  + NX;
  unsigned short* Xv  = Xk  + NX;
  unsigned short* Wq  = Xv  + NX;
  unsigned short* Wk  = Wq  + NW;
  unsigned short* Wv  = Wk  + NW;
  unsigned short* Wo  = Wv  + NW;
  unsigned short* Qbf = Wo  + NW;
  unsigned short* Kbf = Qbf + NX;
  unsigned short* Vtb = Kbf + NX;
  unsigned short* Obf = Vtb + NX;

  float* out  = (float*)d_out;
  float* attn = out + NX;

  cvt7<<<dim3(2048), dim3(256), 0, stream>>>(query, key, value, w_q, w_k, w_v, w_o,
                                             Xq, Xk, Xv, Wq, Wk, Wv, Wo);
  gemm_qkv<<<dim3(Mn / 128, Dn / 128, 3), dim3(256), 0, stream>>>(
      Xq, Xk, Xv, Wq, Wk, Wv, Qbf, Kbf, Vtb);
  attn_fused<<<dim3(64 * 32), dim3(128), 0, stream>>>(Qbf, Kbf, Vtb, attn, Obf);
  gemm_o<<<dim3(Mn / 128, Dn / 128), dim3(256), 0, stream>>>(Obf, Wo, out, b_o);
}